// Round 1
// baseline (119.029 us; speedup 1.0000x reference)
//
#include <hip/hip_runtime.h>

typedef short s16x8 __attribute__((ext_vector_type(8)));
typedef float fx4 __attribute__((ext_vector_type(4)));

#define NROWS 65536
#define BM 64
#define PSTR 129   // params row stride (floats); 129 mod 32 = 1 -> 2-way max bank alias

#define MFMA(a, b, c) __builtin_amdgcn_mfma_f32_16x16x32_bf16((a), (b), (c), 0, 0, 0)

__device__ __forceinline__ unsigned short f2bf(float f) {
  union { float f; unsigned u; } v; v.f = f;
  unsigned r = v.u + 0x7fffu + ((v.u >> 16) & 1u);  // RNE
  return (unsigned short)(r >> 16);
}

// ---------------------------------------------------------------------------
// Pack kernel: fp32 -> bf16, pre-permuted into MFMA B-fragment order.
// W2P  idx = ((ks*4+kc)*256 + n)*8 + e   ; holds W2[ks*32+kc*8+e][n]
// W3P  idx = (((t*8+ks)*4+kc)*128 + n)*8 + e ; n<64 -> V col t*65+n, else W col 520+t*64+(n-64)
// W3X  idx = ((ks*4+kc)*16 + n)*8 + e    ; n<8 -> V col n*65+64 (the 65th V), else 0
// ---------------------------------------------------------------------------
__global__ void pack_weights(const float* __restrict__ W2, const float* __restrict__ W3,
                             unsigned short* __restrict__ W2P, unsigned short* __restrict__ W3P,
                             unsigned short* __restrict__ W3X) {
  int idx = blockIdx.x * 256 + threadIdx.x;
  if (idx < 65536) {
    int e = idx & 7, n = (idx >> 3) & 255, kc = (idx >> 11) & 3, ks = idx >> 13;
    int k = ks * 32 + kc * 8 + e;
    W2P[idx] = f2bf(W2[k * 256 + n]);
  }
  int i3 = idx - 65536;
  if (i3 >= 0 && i3 < 262144) {
    int e = i3 & 7, n = (i3 >> 3) & 127, kc = (i3 >> 10) & 3, ks = (i3 >> 12) & 7, t = i3 >> 15;
    int k = ks * 32 + kc * 8 + e;
    int c = (n < 64) ? (t * 65 + n) : (520 + t * 64 + (n - 64));
    W3P[i3] = f2bf(W3[k * 1032 + c]);
  }
  int ix = idx - 327680;
  if (ix >= 0 && ix < 4096) {
    int e = ix & 7, n = (ix >> 3) & 15, kc = (ix >> 7) & 3, ks = ix >> 9;
    int k = ks * 32 + kc * 8 + e;
    float v = (n < 8) ? W3[k * 1032 + n * 65 + 64] : 0.0f;
    W3X[ix] = f2bf(v);
  }
}

// ---------------------------------------------------------------------------
// Fused MLP + piecewise-quadratic transform. 256 threads (4 waves), 64 rows/block.
// LDS map (55552 B total -> 2 blocks/CU):
//   R1 [0,33024)      : h1/h bf16 [64][256] XOR-swizzled; later params f32 [64][129]
//   RS [33024,49408)  : W3 stage, 2 x 8192 B double buffer
//   xt [49408,51456)  : [64][8] f32
//   v64[51456,53504)  : [64][8] f32 (raw 65th-V params)
//   xc [53504,55552)  : [64][8] f32 ; reused as lj [64][8] in phase 4
// ---------------------------------------------------------------------------
__global__ __launch_bounds__(256, 2) void fused_pwquad(
    const float* __restrict__ x, const float* __restrict__ W1, const float* __restrict__ b1,
    const float* __restrict__ b2, const float* __restrict__ b3,
    const unsigned short* __restrict__ W2P, const unsigned short* __restrict__ W3P,
    const unsigned short* __restrict__ W3X, float* __restrict__ out)
{
  __shared__ char smem[55552];
  char*  R1    = smem;
  char*  RS    = smem + 33024;
  float* xt_s  = (float*)(smem + 49408);
  float* v64_s = (float*)(smem + 51456);
  float* xc_s  = (float*)(smem + 53504);

  const int tid  = threadIdx.x;
  const int lane = tid & 63;
  const int w    = tid >> 6;
  const int r0   = blockIdx.x * BM;

  // ---- phase 0: load x tile; emit copied (even) z cols; stash xc/xt ----
  {
    const float4* xin = (const float4*)(x + (size_t)r0 * 16);
    float4 v = xin[tid];
    int row = tid >> 2, q = tid & 3;
    out[(size_t)(r0 + row) * 16 + 4 * q + 0] = fminf(v.x, 1.0f);
    out[(size_t)(r0 + row) * 16 + 4 * q + 2] = fminf(v.z, 1.0f);
    xc_s[row * 8 + 2 * q]     = v.x;
    xc_s[row * 8 + 2 * q + 1] = v.z;
    xt_s[row * 8 + 2 * q]     = v.y;
    xt_s[row * 8 + 2 * q + 1] = v.w;
  }
  __syncthreads();

  // ---- phase 1: h1 = xc@W1 + b1 (K=8, VALU) -> R1 bf16 swizzled ----
  {
    float w1r[8];
    #pragma unroll
    for (int k = 0; k < 8; k++) w1r[k] = W1[k * 256 + tid];
    float bb = b1[tid];
    #pragma unroll 4
    for (int r = 0; r < 64; r++) {
      float acc = bb;
      #pragma unroll
      for (int k = 0; k < 8; k++) acc += xc_s[r * 8 + k] * w1r[k];
      int byte = (r << 9) + (tid << 1);
      byte ^= ((r & 7) << 4);
      *(unsigned short*)(R1 + byte) = f2bf(acc);
    }
  }
  __syncthreads();

  // ---- phase 2: h = relu(h1@W2 + b2); wave w owns cols [w*64, w*64+64) ----
  fx4 acc2[4][4];
  #pragma unroll
  for (int m = 0; m < 4; m++)
    #pragma unroll
    for (int nt = 0; nt < 4; nt++) acc2[m][nt] = (fx4){0.f, 0.f, 0.f, 0.f};

  #pragma unroll 2
  for (int ks = 0; ks < 8; ks++) {
    s16x8 a[4], b[4];
    #pragma unroll
    for (int m = 0; m < 4; m++) {
      int row = m * 16 + (lane & 15);
      int byte = (row << 9) + ks * 64 + ((lane >> 4) << 4);
      byte ^= ((row & 7) << 4);
      a[m] = *(const s16x8*)(R1 + byte);
    }
    #pragma unroll
    for (int nt = 0; nt < 4; nt++) {
      int n = w * 64 + nt * 16 + (lane & 15);
      size_t off = ((size_t)(ks * 4 + (lane >> 4)) * 256 + n) * 8;
      b[nt] = *(const s16x8*)(W2P + off);
    }
    #pragma unroll
    for (int m = 0; m < 4; m++)
      #pragma unroll
      for (int nt = 0; nt < 4; nt++) acc2[m][nt] = MFMA(a[m], b[nt], acc2[m][nt]);
  }
  __syncthreads();  // all h1 reads done before aliasing R1 with h
  {
    #pragma unroll
    for (int nt = 0; nt < 4; nt++) {
      int col = w * 64 + nt * 16 + (lane & 15);
      float bias = b2[col];
      #pragma unroll
      for (int m = 0; m < 4; m++) {
        #pragma unroll
        for (int rg = 0; rg < 4; rg++) {
          int row = m * 16 + ((lane >> 4) << 2) + rg;
          float v = fmaxf(acc2[m][nt][rg] + bias, 0.0f);
          int byte = (row << 9) + (col << 1);
          byte ^= ((row & 7) << 4);
          *(unsigned short*)(R1 + byte) = f2bf(v);
        }
      }
    }
  }
  __syncthreads();

  // ---- phase 3: hoist GEMM3 A-frags (wave's 16 rows, all K) to regs; V65 GEMM ----
  s16x8 a3[8];
  #pragma unroll
  for (int ks = 0; ks < 8; ks++) {
    int row = w * 16 + (lane & 15);
    int byte = (row << 9) + ks * 64 + ((lane >> 4) << 4);
    byte ^= ((row & 7) << 4);
    a3[ks] = *(const s16x8*)(R1 + byte);
  }
  {
    fx4 accx = (fx4){0.f, 0.f, 0.f, 0.f};
    #pragma unroll
    for (int ks = 0; ks < 8; ks++) {
      size_t off = ((size_t)(ks * 4 + (lane >> 4)) * 16 + (lane & 15)) * 8;
      s16x8 bx = *(const s16x8*)(W3X + off);
      accx = MFMA(a3[ks], bx, accx);
    }
    int tcol = lane & 15;
    if (tcol < 8) {
      float bias = b3[tcol * 65 + 64];
      #pragma unroll
      for (int rg = 0; rg < 4; rg++) {
        int row = w * 16 + ((lane >> 4) << 2) + rg;
        v64_s[row * 8 + tcol] = accx[rg] + bias;
      }
    }
  }
  __syncthreads();  // R1 free -> params; v64 ready

  float* params = (float*)R1;
  float* lj     = xc_s;  // xc dead after phase 1

  for (int t = 0; t < 8; t++) {
    const char* slab = (const char*)(W3P + (size_t)t * 32768);  // 8 ksteps x 8192 B

    // stage ks=0 into buf0 (each wave stages its 2 KB slice)
    {
      const char* g = slab + w * 2048 + lane * 16;
      s16x8 s0 = *(const s16x8*)(g);
      s16x8 s1 = *(const s16x8*)(g + 1024);
      char* d = RS + w * 2048 + lane * 16;
      *(s16x8*)(d) = s0;
      *(s16x8*)(d + 1024) = s1;
    }

    fx4 acc3[8];
    #pragma unroll
    for (int nt = 0; nt < 8; nt++) acc3[nt] = (fx4){0.f, 0.f, 0.f, 0.f};

    for (int ks = 0; ks < 8; ks++) {
      __syncthreads();  // buf[ks&1] visible; buf[(ks+1)&1] readers (ks-1) done
      s16x8 p0 = {}, p1 = {};
      if (ks < 7) {  // issue next-slab loads early (hide HBM/L2 latency under MFMAs)
        const char* g = slab + (ks + 1) * 8192 + w * 2048 + lane * 16;
        p0 = *(const s16x8*)(g);
        p1 = *(const s16x8*)(g + 1024);
      }
      const char* sb = RS + (ks & 1) * 8192;
      #pragma unroll
      for (int nt = 0; nt < 8; nt++) {
        int off = (((lane >> 4) * 128) + nt * 16 + (lane & 15)) * 16;
        s16x8 bf = *(const s16x8*)(sb + off);
        acc3[nt] = MFMA(a3[ks], bf, acc3[nt]);
      }
      if (ks < 7) {  // write-late into the other buffer
        char* d = RS + ((ks + 1) & 1) * 8192 + w * 2048 + lane * 16;
        *(s16x8*)(d) = p0;
        *(s16x8*)(d + 1024) = p1;
      }
    }

    // epilogue: params[row][0..64]=Vun (64 from GEMM; [64] read from v64_s later),
    //           params[row][65..128]=Wun
    #pragma unroll
    for (int nt = 0; nt < 8; nt++) {
      int n = nt * 16 + (lane & 15);
      float bias = (n < 64) ? b3[t * 65 + n] : b3[520 + t * 64 + (n - 64)];
      int ci = (n < 64) ? n : (n + 1);
      #pragma unroll
      for (int rg = 0; rg < 4; rg++) {
        int row = w * 16 + ((lane >> 4) << 2) + rg;
        params[row * PSTR + ci] = acc3[nt][rg] + bias;
      }
    }
    __syncthreads();

    // ---------- postprocess channel t: 4 lanes per row ----------
    {
      int row = tid >> 2, sub = tid & 3;
      const float* prow = params + row * PSTR;
      float xtv = xt_s[row * 8 + t];

      float wj[16];
      float wmax = -3.0e38f;
      #pragma unroll
      for (int j = 0; j < 16; j++) {
        wj[j] = prow[65 + sub * 16 + j];
        wmax = fmaxf(wmax, wj[j]);
      }
      wmax = fmaxf(wmax, __shfl_xor(wmax, 1, 64));
      wmax = fmaxf(wmax, __shfl_xor(wmax, 2, 64));

      float esum = 0.0f;
      #pragma unroll
      for (int j = 0; j < 16; j++) { wj[j] = __expf(wj[j] - wmax); esum += wj[j]; }

      int gbase = lane & ~3;
      float g0 = __shfl(esum, gbase + 0, 64);
      float g1 = __shfl(esum, gbase + 1, 64);
      float g2 = __shfl(esum, gbase + 2, 64);
      float g3 = __shfl(esum, gbase + 3, 64);
      float S = (g0 + g1) + (g2 + g3);
      float invS = 1.0f / S;
      float ebase = 0.0f;
      if (sub > 0) ebase += g0;
      if (sub > 1) ebase += g1;
      if (sub > 2) ebase += g2;

      float ev[17];
      #pragma unroll
      for (int i = 0; i < 16; i++) ev[i] = __expf(prow[sub * 16 + i]);
      ev[16] = __expf((sub < 3) ? prow[sub * 16 + 16] : v64_s[row * 8 + t]);

      float dl = 0.0f;
      #pragma unroll
      for (int j = 0; j < 16; j++) dl += 0.5f * (ev[j] + ev[j + 1]) * (wj[j] * invS);
      float d0 = __shfl(dl, gbase + 0, 64);
      float d1 = __shfl(dl, gbase + 1, 64);
      float d2 = __shfl(dl, gbase + 2, 64);
      float d3 = __shfl(dl, gbase + 3, 64);
      float denom = (d0 + d1) + (d2 + d3);
      float cbase = 0.0f;
      if (sub > 0) cbase += d0;
      if (sub > 1) cbase += d1;
      if (sub > 2) cbase += d2;

      // cumsum + first-crossing search (global prefix via ebase)
      float run = ebase * invS;
      int bloc = 64, jb = 0;
      float wpad = 0.0f, wbb = 1.0f;
      #pragma unroll
      for (int j = 0; j < 16; j++) {
        float wbj = wj[j] * invS;
        float nw = run + wbj;
        bool hit = (bloc == 64) && (nw > xtv);
        if (hit) { bloc = sub * 16 + j; jb = j; wpad = run; wbb = wbj; }
        run = nw;
      }
      int bmin = min(bloc, __shfl_xor(bloc, 1, 64));
      bmin = min(bmin, __shfl_xor(bmin, 2, 64));
      bool fellback = (bmin == 64);
      if (fellback) bmin = 63;  // no crossing (xt >= Wcum[63]): continuous fallback

      if (sub == (bmin >> 4)) {
        if (fellback) { jb = 15; wbb = wj[15] * invS; wpad = run - wbb; }
        float cpart = 0.0f;
        #pragma unroll
        for (int j = 0; j < 16; j++)
          if (j < jb) cpart += 0.5f * (ev[j] + ev[j + 1]) * (wj[j] * invS);
        float evb = 0.0f, evb1 = 0.0f;
        #pragma unroll
        for (int j = 0; j < 16; j++)
          if (j == jb) { evb = ev[j]; evb1 = ev[j + 1]; }
        float alpha = (xtv - wpad) / wbb;
        float Cnum = (0.5f * alpha * alpha * (evb1 - evb) + alpha * evb) * wbb + (cbase + cpart);
        out[(size_t)(r0 + row) * 16 + 2 * t + 1] = fminf(Cnum / denom, 1.0f);
        float qn = evb + alpha * (evb1 - evb);
        lj[row * 8 + t] = __logf(qn) - __logf(denom);
      }
    }
    __syncthreads();
  }

  // ---- log_J = sum_t log(q_t) ----
  if (tid < 64) {
    float s = 0.0f;
    #pragma unroll
    for (int t = 0; t < 8; t++) s += lj[tid * 8 + t];
    out[(size_t)NROWS * 16 + r0 + tid] = s;
  }
}

extern "C" void kernel_launch(void* const* d_in, const int* in_sizes, int n_in,
                              void* d_out, int out_size, void* d_ws, size_t ws_size,
                              hipStream_t stream) {
  const float* x  = (const float*)d_in[0];
  const float* W1 = (const float*)d_in[1];
  const float* b1 = (const float*)d_in[2];
  const float* W2 = (const float*)d_in[3];
  const float* b2 = (const float*)d_in[4];
  const float* W3 = (const float*)d_in[5];
  const float* b3 = (const float*)d_in[6];

  unsigned short* W2P = (unsigned short*)d_ws;                       // 131072 B
  unsigned short* W3P = (unsigned short*)((char*)d_ws + 131072);     // 524288 B
  unsigned short* W3X = (unsigned short*)((char*)d_ws + 655360);     // 8192 B

  pack_weights<<<dim3(1296), dim3(256), 0, stream>>>(W2, W3, W2P, W3P, W3X);
  fused_pwquad<<<dim3(NROWS / BM), dim3(256), 0, stream>>>(
      x, W1, b1, b2, b3, W2P, W3P, W3X, (float*)d_out);
}

// Round 2
// 99.655 us; speedup vs baseline: 1.1944x; 1.1944x over previous
//
#include <hip/hip_runtime.h>

typedef short s16x8 __attribute__((ext_vector_type(8)));
typedef float fx4 __attribute__((ext_vector_type(4)));

#define NROWS 65536
#define BM 64
#define PSTR 133   // params row stride (floats); 5*row pattern -> conflict-free reads

#define MFMA(a, b, c) __builtin_amdgcn_mfma_f32_16x16x32_bf16((a), (b), (c), 0, 0, 0)

__device__ __forceinline__ unsigned short f2bf(float f) {
  union { float f; unsigned u; } v; v.f = f;
  unsigned r = v.u + 0x7fffu + ((v.u >> 16) & 1u);  // RNE
  return (unsigned short)(r >> 16);
}

// LDS-only barrier: does NOT drain vmcnt, so in-flight global loads/stores
// (out[] stores, B-prefetch) survive. All cross-wave handoffs here are LDS.
__device__ __forceinline__ void bar_lds() {
  asm volatile("s_waitcnt lgkmcnt(0)\n\ts_barrier" ::: "memory");
}

// ---------------------------------------------------------------------------
// Pack kernel: fp32 -> bf16, pre-permuted into MFMA B-fragment order.
// W2P  idx = ((ks*4+kc)*256 + n)*8 + e   ; holds W2[ks*32+kc*8+e][n]
// W3P  idx = (((t*8+ks)*4+kc)*128 + n)*8 + e ; n<64 -> V col t*65+n, else W col 520+t*64+(n-64)
// W3X  idx = ((ks*4+kc)*16 + n)*8 + e    ; n<8 -> V col n*65+64 (the 65th V), else 0
// ---------------------------------------------------------------------------
__global__ void pack_weights(const float* __restrict__ W2, const float* __restrict__ W3,
                             unsigned short* __restrict__ W2P, unsigned short* __restrict__ W3P,
                             unsigned short* __restrict__ W3X) {
  int idx = blockIdx.x * 256 + threadIdx.x;
  if (idx < 65536) {
    int e = idx & 7, n = (idx >> 3) & 255, kc = (idx >> 11) & 3, ks = idx >> 13;
    int k = ks * 32 + kc * 8 + e;
    W2P[idx] = f2bf(W2[k * 256 + n]);
  }
  int i3 = idx - 65536;
  if (i3 >= 0 && i3 < 262144) {
    int e = i3 & 7, n = (i3 >> 3) & 127, kc = (i3 >> 10) & 3, ks = (i3 >> 12) & 7, t = i3 >> 15;
    int k = ks * 32 + kc * 8 + e;
    int c = (n < 64) ? (t * 65 + n) : (520 + t * 64 + (n - 64));
    W3P[i3] = f2bf(W3[k * 1032 + c]);
  }
  int ix = idx - 327680;
  if (ix >= 0 && ix < 4096) {
    int e = ix & 7, n = (ix >> 3) & 15, kc = (ix >> 7) & 3, ks = ix >> 9;
    int k = ks * 32 + kc * 8 + e;
    float v = (n < 8) ? W3[k * 1032 + n * 65 + 64] : 0.0f;
    W3X[ix] = f2bf(v);
  }
}

// ---------------------------------------------------------------------------
// Fused MLP + piecewise-quadratic transform. 256 threads (4 waves), 64 rows/block.
// GEMM3 col-partitioned (wave w: cols [32w,32w+32), all 64 rows, B direct from L2).
// Postprocess row-partitioned (wave w: rows [16w,16w+16)) -> one barrier per t.
// LDS map (74240 B -> 2 blocks/CU):
//   P0 [0,34048)       : params buf0 f32 [64][133]; h1/h bf16 [64][256] swizzled aliases it
//   P1 [34048,68096)   : params buf1
//   xt [68096,70144)   : [64][8] f32
//   v64[70144,72192)   : [64][8] f32 (raw 65th-V params)
//   xc [72192,74240)   : [64][8] f32 ; reused as lj [64][8] in t-loop
// ---------------------------------------------------------------------------
__global__ __launch_bounds__(256, 2) void fused_pwquad(
    const float* __restrict__ x, const float* __restrict__ W1, const float* __restrict__ b1,
    const float* __restrict__ b2, const float* __restrict__ b3,
    const unsigned short* __restrict__ W2P, const unsigned short* __restrict__ W3P,
    const unsigned short* __restrict__ W3X, float* __restrict__ out)
{
  __shared__ char smem[74240];
  char*  H     = smem;                      // h1/h, aliases P0
  float* P0    = (float*)smem;
  float* P1    = (float*)(smem + 34048);
  float* xt_s  = (float*)(smem + 68096);
  float* v64_s = (float*)(smem + 70144);
  float* xc_s  = (float*)(smem + 72192);
  float* lj    = xc_s;  // xc dead after phase 1

  const int tid  = threadIdx.x;
  const int lane = tid & 63;
  const int w    = tid >> 6;
  const int r0   = blockIdx.x * BM;

  // ---- phase 0: load x tile; emit copied (even) z cols; stash xc/xt ----
  {
    const float4* xin = (const float4*)(x + (size_t)r0 * 16);
    float4 v = xin[tid];
    int row = tid >> 2, q = tid & 3;
    out[(size_t)(r0 + row) * 16 + 4 * q + 0] = fminf(v.x, 1.0f);
    out[(size_t)(r0 + row) * 16 + 4 * q + 2] = fminf(v.z, 1.0f);
    xc_s[row * 8 + 2 * q]     = v.x;
    xc_s[row * 8 + 2 * q + 1] = v.z;
    xt_s[row * 8 + 2 * q]     = v.y;
    xt_s[row * 8 + 2 * q + 1] = v.w;
  }
  bar_lds();

  // ---- phase 1: h1 = xc@W1 + b1 (K=8, VALU) -> H bf16 swizzled ----
  {
    float w1r[8];
    #pragma unroll
    for (int k = 0; k < 8; k++) w1r[k] = W1[k * 256 + tid];
    float bb = b1[tid];
    #pragma unroll 4
    for (int r = 0; r < 64; r++) {
      float acc = bb;
      #pragma unroll
      for (int k = 0; k < 8; k++) acc += xc_s[r * 8 + k] * w1r[k];
      int byte = (r << 9) + (tid << 1);
      byte ^= ((r & 7) << 4);
      *(unsigned short*)(H + byte) = f2bf(acc);
    }
  }
  bar_lds();

  // ---- phase 2: h = relu(h1@W2 + b2); wave w owns cols [w*64, w*64+64) ----
  fx4 acc2[4][4];
  #pragma unroll
  for (int m = 0; m < 4; m++)
    #pragma unroll
    for (int nt = 0; nt < 4; nt++) acc2[m][nt] = (fx4){0.f, 0.f, 0.f, 0.f};

  #pragma unroll 2
  for (int ks = 0; ks < 8; ks++) {
    s16x8 a[4], b[4];
    #pragma unroll
    for (int m = 0; m < 4; m++) {
      int row = m * 16 + (lane & 15);
      int byte = (row << 9) + ks * 64 + ((lane >> 4) << 4);
      byte ^= ((row & 7) << 4);
      a[m] = *(const s16x8*)(H + byte);
    }
    #pragma unroll
    for (int nt = 0; nt < 4; nt++) {
      int n = w * 64 + nt * 16 + (lane & 15);
      size_t off = ((size_t)(ks * 4 + (lane >> 4)) * 256 + n) * 8;
      b[nt] = *(const s16x8*)(W2P + off);
    }
    #pragma unroll
    for (int m = 0; m < 4; m++)
      #pragma unroll
      for (int nt = 0; nt < 4; nt++) acc2[m][nt] = MFMA(a[m], b[nt], acc2[m][nt]);
  }
  bar_lds();  // all h1 reads done before aliasing H with h
  {
    #pragma unroll
    for (int nt = 0; nt < 4; nt++) {
      int col = w * 64 + nt * 16 + (lane & 15);
      float bias = b2[col];
      #pragma unroll
      for (int m = 0; m < 4; m++) {
        #pragma unroll
        for (int rg = 0; rg < 4; rg++) {
          int row = m * 16 + ((lane >> 4) << 2) + rg;
          float v = fmaxf(acc2[m][nt][rg] + bias, 0.0f);
          int byte = (row << 9) + (col << 1);
          byte ^= ((row & 7) << 4);
          *(unsigned short*)(H + byte) = f2bf(v);
        }
      }
    }
  }
  bar_lds();

  // ---- phase 3: hoist GEMM3 A-frags for ALL 64 rows to regs; V65 GEMM ----
  s16x8 a3[4][8];
  #pragma unroll
  for (int m = 0; m < 4; m++) {
    #pragma unroll
    for (int ks = 0; ks < 8; ks++) {
      int row = m * 16 + (lane & 15);
      int byte = (row << 9) + ks * 64 + ((lane >> 4) << 4);
      byte ^= ((row & 7) << 4);
      a3[m][ks] = *(const s16x8*)(H + byte);
    }
  }
  #pragma unroll
  for (int m = 0; m < 4; m++) {
    if (m == w) {  // wave-uniform: compute V65 only for this wave's rows
      fx4 accx = (fx4){0.f, 0.f, 0.f, 0.f};
      #pragma unroll
      for (int ks = 0; ks < 8; ks++) {
        size_t off = ((size_t)(ks * 4 + (lane >> 4)) * 16 + (lane & 15)) * 8;
        s16x8 bx = *(const s16x8*)(W3X + off);
        accx = MFMA(a3[m][ks], bx, accx);
      }
      int tcol = lane & 15;
      if (tcol < 8) {
        float bias = b3[tcol * 65 + 64];
        #pragma unroll
        for (int rg = 0; rg < 4; rg++) {
          int row = m * 16 + ((lane >> 4) << 2) + rg;
          v64_s[row * 8 + tcol] = accx[rg] + bias;
        }
      }
    }
  }
  bar_lds();  // H free -> params buf0; v64/xt visible

  // B-frag prefetch for (t=0, ks=0)
  const int kc = lane >> 4, l15 = lane & 15;
  s16x8 bpre0, bpre1;
  {
    const unsigned short* bp = W3P + ((size_t)(kc)*128 + w * 32 + l15) * 8;
    bpre0 = *(const s16x8*)(bp);
    bpre1 = *(const s16x8*)(bp + 128);
  }

  for (int t = 0; t < 8; t++) {
    float* params = (t & 1) ? P1 : P0;

    fx4 acc3[4][2];
    #pragma unroll
    for (int m = 0; m < 4; m++) { acc3[m][0] = (fx4){0.f,0.f,0.f,0.f}; acc3[m][1] = (fx4){0.f,0.f,0.f,0.f}; }

    // ks = 0 uses prefetched B
    #pragma unroll
    for (int m = 0; m < 4; m++) {
      acc3[m][0] = MFMA(a3[m][0], bpre0, acc3[m][0]);
      acc3[m][1] = MFMA(a3[m][0], bpre1, acc3[m][1]);
    }
    #pragma unroll
    for (int ks = 1; ks < 8; ks++) {
      const unsigned short* bp = W3P + ((size_t)((t * 8 + ks) * 4 + kc) * 128 + w * 32 + l15) * 8;
      s16x8 b0 = *(const s16x8*)(bp);
      s16x8 b1 = *(const s16x8*)(bp + 128);
      #pragma unroll
      for (int m = 0; m < 4; m++) {
        acc3[m][0] = MFMA(a3[m][ks], b0, acc3[m][0]);
        acc3[m][1] = MFMA(a3[m][ks], b1, acc3[m][1]);
      }
    }

    // epilogue: wave w writes cols [32w,32w+32) for all 64 rows
    #pragma unroll
    for (int nt = 0; nt < 2; nt++) {
      int n = w * 32 + nt * 16 + l15;              // 0..127 within channel t
      bool isV = (n < 64);                          // wave-uniform
      float bias = isV ? b3[t * 65 + n] : b3[520 + t * 64 + (n - 64)];
      int ci = isV ? n : (n + 1);                   // hole at 64 (V65 in v64_s)
      #pragma unroll
      for (int m = 0; m < 4; m++) {
        #pragma unroll
        for (int rg = 0; rg < 4; rg++) {
          int row = m * 16 + (kc << 2) + rg;
          params[row * PSTR + ci] = acc3[m][nt][rg] + bias;
        }
      }
    }

    // prefetch B for (t+1, ks=0) — stays in flight across the LDS-only barrier,
    // L2 latency hides under postprocess
    if (t < 7) {
      const unsigned short* bp = W3P + ((size_t)((t + 1) * 32 + kc) * 128 + w * 32 + l15) * 8;
      bpre0 = *(const s16x8*)(bp);
      bpre1 = *(const s16x8*)(bp + 128);
    }

    bar_lds();  // params[t&1] complete

    // ---------- postprocess channel t: wave w rows [16w,16w+16), 4 lanes/row ----------
    {
      int row = w * 16 + (lane >> 2), sub = lane & 3;
      const float* prow = params + row * PSTR;
      float xtv = xt_s[row * 8 + t];

      float wj[16];
      float wmax = -3.0e38f;
      #pragma unroll
      for (int j = 0; j < 16; j++) {
        wj[j] = prow[65 + sub * 16 + j];
        wmax = fmaxf(wmax, wj[j]);
      }
      wmax = fmaxf(wmax, __shfl_xor(wmax, 1, 64));
      wmax = fmaxf(wmax, __shfl_xor(wmax, 2, 64));

      float esum = 0.0f;
      #pragma unroll
      for (int j = 0; j < 16; j++) { wj[j] = __expf(wj[j] - wmax); esum += wj[j]; }

      int gbase = lane & ~3;
      float g0 = __shfl(esum, gbase + 0, 64);
      float g1 = __shfl(esum, gbase + 1, 64);
      float g2 = __shfl(esum, gbase + 2, 64);
      float g3 = __shfl(esum, gbase + 3, 64);
      float S = (g0 + g1) + (g2 + g3);
      float invS = 1.0f / S;
      float ebase = 0.0f;
      if (sub > 0) ebase += g0;
      if (sub > 1) ebase += g1;
      if (sub > 2) ebase += g2;

      float ev[17];
      #pragma unroll
      for (int i = 0; i < 16; i++) ev[i] = __expf(prow[sub * 16 + i]);
      ev[16] = __expf((sub < 3) ? prow[sub * 16 + 16] : v64_s[row * 8 + t]);

      float dl = 0.0f;
      #pragma unroll
      for (int j = 0; j < 16; j++) dl += 0.5f * (ev[j] + ev[j + 1]) * (wj[j] * invS);
      float d0 = __shfl(dl, gbase + 0, 64);
      float d1 = __shfl(dl, gbase + 1, 64);
      float d2 = __shfl(dl, gbase + 2, 64);
      float d3 = __shfl(dl, gbase + 3, 64);
      float denom = (d0 + d1) + (d2 + d3);
      float cbase = 0.0f;
      if (sub > 0) cbase += d0;
      if (sub > 1) cbase += d1;
      if (sub > 2) cbase += d2;

      // cumsum + first-crossing search (global prefix via ebase)
      float run = ebase * invS;
      int bloc = 64, jb = 0;
      float wpad = 0.0f, wbb = 1.0f;
      #pragma unroll
      for (int j = 0; j < 16; j++) {
        float wbj = wj[j] * invS;
        float nw = run + wbj;
        bool hit = (bloc == 64) && (nw > xtv);
        if (hit) { bloc = sub * 16 + j; jb = j; wpad = run; wbb = wbj; }
        run = nw;
      }
      int bmin = min(bloc, __shfl_xor(bloc, 1, 64));
      bmin = min(bmin, __shfl_xor(bmin, 2, 64));
      bool fellback = (bmin == 64);
      if (fellback) bmin = 63;  // no crossing (xt >= Wcum[63]): continuous fallback

      if (sub == (bmin >> 4)) {
        if (fellback) { jb = 15; wbb = wj[15] * invS; wpad = run - wbb; }
        float cpart = 0.0f;
        #pragma unroll
        for (int j = 0; j < 16; j++)
          if (j < jb) cpart += 0.5f * (ev[j] + ev[j + 1]) * (wj[j] * invS);
        float evb = 0.0f, evb1 = 0.0f;
        #pragma unroll
        for (int j = 0; j < 16; j++)
          if (j == jb) { evb = ev[j]; evb1 = ev[j + 1]; }
        float alpha = (xtv - wpad) / wbb;
        float Cnum = (0.5f * alpha * alpha * (evb1 - evb) + alpha * evb) * wbb + (cbase + cpart);
        out[(size_t)(r0 + row) * 16 + 2 * t + 1] = fminf(Cnum / denom, 1.0f);
        float qn = evb + alpha * (evb1 - evb);
        lj[row * 8 + t] = __logf(qn) - __logf(denom);
      }
    }
    // no barrier: epilogue(t+1) writes the other params buffer; the WAR on
    // params[t&1] from epilogue(t+2) is ordered by barrier(t+1)
  }

  // ---- log_J = sum_t log(q_t): wave w emits its own 16 rows (intra-wave lj) ----
  if ((lane & 48) == 0 && lane < 16) {
    int row = w * 16 + lane;
    float s = 0.0f;
    #pragma unroll
    for (int t = 0; t < 8; t++) s += lj[row * 8 + t];
    out[(size_t)NROWS * 16 + r0 + row] = s;
  }
}

extern "C" void kernel_launch(void* const* d_in, const int* in_sizes, int n_in,
                              void* d_out, int out_size, void* d_ws, size_t ws_size,
                              hipStream_t stream) {
  const float* x  = (const float*)d_in[0];
  const float* W1 = (const float*)d_in[1];
  const float* b1 = (const float*)d_in[2];
  const float* W2 = (const float*)d_in[3];
  const float* b2 = (const float*)d_in[4];
  const float* W3 = (const float*)d_in[5];
  const float* b3 = (const float*)d_in[6];

  unsigned short* W2P = (unsigned short*)d_ws;                       // 131072 B
  unsigned short* W3P = (unsigned short*)((char*)d_ws + 131072);     // 524288 B
  unsigned short* W3X = (unsigned short*)((char*)d_ws + 655360);     // 8192 B

  pack_weights<<<dim3(1296), dim3(256), 0, stream>>>(W2, W3, W2P, W3P, W3X);
  fused_pwquad<<<dim3(NROWS / BM), dim3(256), 0, stream>>>(
      x, W1, b1, b2, b3, W2P, W3P, W3X, (float*)d_out);
}